// Round 3
// baseline (67.833 us; speedup 1.0000x reference)
//
#include <hip/hip_runtime.h>
#include <math.h>

// Problem constants (match reference)
#define PH 256              // pano H
#define PW 512              // pano W
#define NRAYS (PH * PW)     // 131072
#define NS 300              // samples per ray
#define HV 256
#define WV 256
#define DV 64               // voxel depth (without ground)
#define PI_F 3.14159265358979323846f

__device__ __forceinline__ float lerpf(float a, float b, float f) {
    return fmaf(f, b - a, a);
}

// Slow-path trilinear corner fetch from the (ground+voxel) volume, zero
// padding outside. Logical volume: D=65 slices; slice 0 is the constant
// ground plane (1000.0), slices 1..64 map to voxel[0..63].
__device__ __forceinline__ float fetch_vox(const float* __restrict__ vox,
                                           int iz, int iy, int ix) {
    bool valid = ((unsigned)ix < (unsigned)WV) &
                 ((unsigned)iy < (unsigned)HV) &
                 ((unsigned)iz < 65u);
    int czi = iz < 1 ? 1 : (iz > 64 ? 64 : iz);
    int cy = iy < 0 ? 0 : (iy > HV - 1 ? HV - 1 : iy);
    int cx = ix < 0 ? 0 : (ix > WV - 1 ? WV - 1 : ix);
    float v = vox[((czi - 1) << 16) + (cy << 8) + cx];
    if (iz == 0) v = 1000.0f;
    return valid ? v : 0.0f;
}

// Issue 8 corner loads for cell (x0,y0,z0) into the given registers.
// Values are used later; the compiler's s_waitcnt lands at first use.
__device__ __forceinline__ void issue8(const float* __restrict__ vox,
                                       int x0, int y0, int z0,
                                       float& d000, float& d001, float& d010, float& d011,
                                       float& d100, float& d101, float& d110, float& d111) {
    bool interior = ((unsigned)x0 < 255u) &
                    ((unsigned)y0 < 255u) &
                    ((unsigned)(z0 - 1) < 63u);
    if (interior) {
        const float* p = vox + (((z0 - 1) << 16) + (y0 << 8) + x0);
        d000 = p[0];       d001 = p[1];
        d010 = p[256];     d011 = p[257];
        d100 = p[65536];   d101 = p[65537];
        d110 = p[65792];   d111 = p[65793];
    } else {
        d000 = fetch_vox(vox, z0,     y0,     x0);
        d001 = fetch_vox(vox, z0,     y0,     x0 + 1);
        d010 = fetch_vox(vox, z0,     y0 + 1, x0);
        d011 = fetch_vox(vox, z0,     y0 + 1, x0 + 1);
        d100 = fetch_vox(vox, z0 + 1, y0,     x0);
        d101 = fetch_vox(vox, z0 + 1, y0,     x0 + 1);
        d110 = fetch_vox(vox, z0 + 1, y0 + 1, x0);
        d111 = fetch_vox(vox, z0 + 1, y0 + 1, x0 + 1);
    }
}

__global__ __launch_bounds__(256)
void render_kernel(const float* __restrict__ vox,
                   float* __restrict__ out,        // [NRAYS] raw depth, [NRAYS..2*NRAYS) opacity
                   float* __restrict__ blockMin,
                   float* __restrict__ blockMax) {
    const int r = blockIdx.x * 256 + threadIdx.x;
    const int h = r >> 9;       // / PW
    const int w = r & (PW - 1);

    // ray direction
    const float lat = (0.5f - (float)h * (1.0f / 255.0f)) * PI_F;
    const float lon = (-0.5f - 2.0f * (float)w * (1.0f / 511.0f)) * PI_F;
    float cl, sl, clon, slon;
    __sincosf(lat, &sl, &cl);
    __sincosf(lon, &slon, &clon);
    const float dx = cl * clon;
    const float dy = -cl * slon;
    const float dz = sl;
    const float oz = -1.0f + 2.0f * 2.0f / 128.0f;   // -0.96875

    // Per-step deltas in voxel coordinates.
    const float step = 1.0f / (float)NS;
    const float sxd = dx * 128.0f * step;
    const float syd = dy * 128.0f * step;
    const float szd = dz * 65.0f * step;

    const float intv = 64.0f / (float)NS;

    float T = 1.0f;
    float depth = 0.0f;
    float opac = 0.0f;
    float dval = 0.0f;

    // position of sample 0 (t = 1/N)
    float xf = 127.5f + sxd;
    float yf = 127.5f + syd;
    float zf = (oz * 65.0f + 64.5f) + szd;

    // current cell + corners
    int px = (int)floorf(xf);
    int py = (int)floorf(yf);
    int pz = (int)floorf(zf);
    float c000, c001, c010, c011, c100, c101, c110, c111;
    issue8(vox, px, py, pz, c000, c001, c010, c011, c100, c101, c110, c111);

    // pending prefetch state
    bool pend = false;
    int qx = 0, qy = 0, qz = 0;
    float n000 = 0.f, n001 = 0.f, n010 = 0.f, n011 = 0.f;
    float n100 = 0.f, n101 = 0.f, n110 = 0.f, n111 = 0.f;

    for (int i = 0; i < NS; ++i) {
        // consume pending prefetch (s_waitcnt lands here, hidden by prev iter's math)
        if (pend) {
            c000 = n000; c001 = n001; c010 = n010; c011 = n011;
            c100 = n100; c101 = n101; c110 = n110; c111 = n111;
            px = qx; py = qy; pz = qz;
            pend = false;
        }

        // trajectory early-out: fully outside with no return -> all remaining sigma = 0
        if ((pz < -1 && szd <= 0.0f) | (pz > 64 && szd >= 0.0f)) break;

        // fractional coords of current sample
        float fx = xf - (float)px;
        float fy = yf - (float)py;
        float fz = zf - (float)pz;

        // lookahead: position of sample i+1, prefetch its cell if different
        float nxf = xf + sxd;
        float nyf = yf + syd;
        float nzf = zf + szd;
        int ax = (int)floorf(nxf);
        int ay = (int)floorf(nyf);
        int az = (int)floorf(nzf);
        if ((ax != px) | (ay != py) | (az != pz)) {
            issue8(vox, ax, ay, az, n000, n001, n010, n011, n100, n101, n110, n111);
            qx = ax; qy = ay; qz = az;
            pend = true;
        }

        // trilinear + transmittance for current sample
        float l00 = lerpf(c000, c001, fx);
        float l01 = lerpf(c010, c011, fx);
        float l10 = lerpf(c100, c101, fx);
        float l11 = lerpf(c110, c111, fx);
        float lo  = lerpf(l00, l01, fy);
        float hi  = lerpf(l10, l11, fy);
        float sig = lerpf(lo, hi, fz);

        dval += intv;
        float e = __expf(-sig * intv);
        float prob = T - T * e;            // T * (1 - e)
        depth = fmaf(prob, dval, depth);
        opac += prob;
        T *= e;
        if (T < 1e-6f) break;

        xf = nxf; yf = nyf; zf = nzf;
    }

    out[r] = depth;             // raw depth (normalized by a later kernel)
    out[NRAYS + r] = opac;

    // block min/max reduction of depth
    __shared__ float smn[256];
    __shared__ float smx[256];
    const int t = threadIdx.x;
    smn[t] = depth;
    smx[t] = depth;
    __syncthreads();
    #pragma unroll
    for (int s = 128; s > 0; s >>= 1) {
        if (t < s) {
            smn[t] = fminf(smn[t], smn[t + s]);
            smx[t] = fmaxf(smx[t], smx[t + s]);
        }
        __syncthreads();
    }
    if (t == 0) {
        blockMin[blockIdx.x] = smn[0];
        blockMax[blockIdx.x] = smx[0];
    }
}

__global__ __launch_bounds__(512)
void reduce_minmax_kernel(const float* __restrict__ blockMin,
                          const float* __restrict__ blockMax,
                          float* __restrict__ mm) {
    __shared__ float smn[512];
    __shared__ float smx[512];
    const int t = threadIdx.x;
    smn[t] = blockMin[t];
    smx[t] = blockMax[t];
    __syncthreads();
    #pragma unroll
    for (int s = 256; s > 0; s >>= 1) {
        if (t < s) {
            smn[t] = fminf(smn[t], smn[t + s]);
            smx[t] = fmaxf(smx[t], smx[t + s]);
        }
        __syncthreads();
    }
    if (t == 0) {
        mm[0] = smn[0];
        mm[1] = smx[0];
    }
}

__global__ __launch_bounds__(256)
void normalize_kernel(float* __restrict__ out, const float* __restrict__ mm) {
    const int r = blockIdx.x * 256 + threadIdx.x;
    const float mn = mm[0];
    const float mx = mm[1];
    out[r] = (out[r] - mn) / (mx - mn);
}

extern "C" void kernel_launch(void* const* d_in, const int* in_sizes, int n_in,
                              void* d_out, int out_size, void* d_ws, size_t ws_size,
                              hipStream_t stream) {
    const float* vox = (const float*)d_in[0];
    float* out = (float*)d_out;
    float* wsf = (float*)d_ws;
    float* blockMin = wsf;          // 512
    float* blockMax = wsf + 512;    // 512
    float* mm = wsf + 1024;         // 2

    const int nblocks = NRAYS / 256;   // 512
    render_kernel<<<nblocks, 256, 0, stream>>>(vox, out, blockMin, blockMax);
    reduce_minmax_kernel<<<1, 512, 0, stream>>>(blockMin, blockMax, mm);
    normalize_kernel<<<nblocks, 256, 0, stream>>>(out, mm);
}